// Round 1
// 96.341 us; speedup vs baseline: 1.0123x; 1.0123x over previous
//
#include <hip/hip_runtime.h>

// B=8, N=256, M=16, D=256
// loss = sum_rows logsumexp_k(S) - sum S_self, S = w*<e,c_k>+b, LOO diagonal
constexpr int B = 8, N = 256, M = 16, D = 256;

typedef short bf16x8 __attribute__((ext_vector_type(8)));
typedef float f32x4 __attribute__((ext_vector_type(4)));

__device__ __forceinline__ unsigned short f2bf(float x) {
  unsigned u = __float_as_uint(x);
  u = (u + 0x7FFFu + ((u >> 16) & 1u)) >> 16;  // RNE
  return (unsigned short)u;
}
__device__ __forceinline__ uint4 packbf8(const float* f) {
  uint4 u;
  u.x = (unsigned)f2bf(f[0]) | ((unsigned)f2bf(f[1]) << 16);
  u.y = (unsigned)f2bf(f[2]) | ((unsigned)f2bf(f[3]) << 16);
  u.z = (unsigned)f2bf(f[4]) | ((unsigned)f2bf(f[5]) << 16);
  u.w = (unsigned)f2bf(f[6]) | ((unsigned)f2bf(f[7]) << 16);
  return u;
}

// ws: EbfA [0,16MB) A-frags: uint4[(b*256+j)*8+kc][lane], lane l = row m=l&15,
//       dims kc*32+(l>>4)*8..+7.  Cbf [16,17MB) B-frags: uint4[(b*8+kc)*16+nt][lane],
//       lane l = col n=nt*16+(l&15), dims kc*32+(l>>4)*8..+7.  SQ [17MB,+128KB) fp32 row sqnorms.

// k_prep v2: one block per (b,j). Shuffle-free centroid (thread=dim, serial over M),
// A-frag pack + sqnorm from an L1-hot re-read in (row, octet-pair) ownership.
// Per-thread cross-lane ops: 2 shuffles (was 66 ds_bpermute).
__global__ __launch_bounds__(256) void k_prep(const float* __restrict__ e,
                                              uint4* __restrict__ EbfA,
                                              uint4* __restrict__ Cbf,
                                              float* __restrict__ SQ,
                                              float* __restrict__ out) {
  const int blk = blockIdx.x;  // b*256 + j
  const int b = blk >> 8, j = blk & 255;
  const int t = threadIdx.x;
  const float* base = e + (size_t)blk * (M * D);

  __shared__ float cbuf[D];        // centroid, fp32
  __shared__ float sqred[4][16];   // per-wave sqnorm partials

  // ---- Pass 1: centroid. Thread t owns dim d=t; 16 fully-coalesced 1KB loads,
  // zero cross-lane traffic.
  float cs = 0.f;
#pragma unroll
  for (int i = 0; i < M; ++i) cs += base[i * D + t];
  cbuf[t] = cs * (1.f / 16.f);

  // ---- Pass 2: A-frag pack + sqnorm. Thread t -> row m=t&15, octet pair {o2, o2+16}.
  // Re-reads the block's 16KB (L1/L2-hot, fetched concurrently with pass 1).
  const int m = t & 15, o2 = t >> 4;
  const float* p0 = base + m * D + o2 * 8;  // 32B-aligned
  float f0[8], f1[8];
  *(float4*)(f0) = *(const float4*)(p0);
  *(float4*)(f0 + 4) = *(const float4*)(p0 + 4);
  *(float4*)(f1) = *(const float4*)(p0 + 128);
  *(float4*)(f1 + 4) = *(const float4*)(p0 + 132);

  // A-fragment stores: octet o -> slot kc=o>>2, lane (o&3)*16+m.
  // t-ascending => uint4 addresses perfectly sequential (1KB contiguous per wave).
  EbfA[(size_t)(blk * 8 + (o2 >> 2)) * 64 + (o2 & 3) * 16 + m] = packbf8(f0);
  EbfA[(size_t)(blk * 8 + 4 + (o2 >> 2)) * 64 + (o2 & 3) * 16 + m] = packbf8(f1);

  // sqnorm partial: this thread covers dims [o2*8,+8) u [128+o2*8,+8) of row m.
  float sqp = 0.f;
#pragma unroll
  for (int x = 0; x < 8; ++x) sqp = fmaf(f0[x], f0[x], fmaf(f1[x], f1[x], sqp));
  // reduce over o2 low bits (lane bits 4,5); waves hold disjoint dim ranges.
  sqp += __shfl_xor(sqp, 16, 64);
  sqp += __shfl_xor(sqp, 32, 64);
  const int w = t >> 6;
  if ((t & 63) < 16) sqred[w][m] = sqp;
  __syncthreads();

  // ---- Epilogue: centroid B-frag pack (threads 0..31: kc=t>>2, q=t&3, dims t*8..+7)
  if (t < 32) {
    float cf[8];
#pragma unroll
    for (int x = 0; x < 8; ++x) cf[x] = cbuf[t * 8 + x];
    Cbf[((size_t)(b * 8 + (t >> 2)) * 16 + (j >> 4)) * 64 + (t & 3) * 16 + (j & 15)] =
        packbf8(cf);
  }
  if (t < 16) SQ[blk * 16 + t] = sqred[0][t] + sqred[1][t] + sqred[2][t] + sqred[3][t];
  if (blk == 0 && t == 0) out[0] = 0.f;  // d_out re-poisoned each launch
}

// One block per (b, 64-row strip). 4 waves 2x2: h=row-half(2 tiles), c=col-half(8 tiles).
// acc 64 VGPRs/wave; NO dynamic register indexing anywhere.  (UNCHANGED this round.)
__global__ __launch_bounds__(256) void k_gemm(const uint4* __restrict__ EbfA,
                                              const uint4* __restrict__ Cbf,
                                              const float* __restrict__ SQ,
                                              const float* __restrict__ wp,
                                              const float* __restrict__ bp,
                                              float* __restrict__ out) {
  const int blk = blockIdx.x;  // b*64 + strip
  const int b = blk >> 6, strip = blk & 63;
  const int tid = threadIdx.x;
  const int wid = tid >> 6, lane = tid & 63;
  const int h = wid >> 1, c = wid & 1;
  const int q = lane >> 4, cl_ = lane & 15;

  const uint4* Ab = EbfA + (size_t)((b * 256 + strip * 4 + h * 2) * 8) * 64 + lane;
  const uint4* Bb = Cbf + (size_t)(b * 128 + c * 8) * 64 + lane;

  f32x4 acc[2][8];
#pragma unroll
  for (int rt = 0; rt < 2; ++rt)
#pragma unroll
    for (int nt = 0; nt < 8; ++nt) acc[rt][nt] = (f32x4)0.f;

#pragma unroll 1
  for (int kc = 0; kc < 8; ++kc) {
    uint4 af0 = Ab[kc * 64];
    uint4 af1 = Ab[(8 + kc) * 64];
    uint4 bfr[8];
#pragma unroll
    for (int nt = 0; nt < 8; ++nt) bfr[nt] = Bb[(kc * 16 + nt) * 64];
    bf16x8 a0 = __builtin_bit_cast(bf16x8, af0);
    bf16x8 a1 = __builtin_bit_cast(bf16x8, af1);
#pragma unroll
    for (int nt = 0; nt < 8; ++nt) {
      bf16x8 bv = __builtin_bit_cast(bf16x8, bfr[nt]);
      acc[0][nt] = __builtin_amdgcn_mfma_f32_16x16x32_bf16(a0, bv, acc[0][nt], 0, 0, 0);
      acc[1][nt] = __builtin_amdgcn_mfma_f32_16x16x32_bf16(a1, bv, acc[1][nt], 0, 0, 0);
    }
  }

  // ---- epilogue: scale, LOO diagonal, logsumexp ----
  const float w = *wp, bias = *bp;
  __shared__ float lmx[2][64];
  __shared__ float lsm[2][64];
  __shared__ float bred[4];
  float ssum = 0.f;

#pragma unroll
  for (int rt = 0; rt < 2; ++rt) {
    const int jr = strip * 4 + h * 2 + rt;          // global row-tile == diag col
    const bool own = (c == (jr >> 7)) && (cl_ == (jr & 15));
    const int ntd = (jr >> 4) & 7;
    float sq[4];
    if (own) {
#pragma unroll
      for (int reg = 0; reg < 4; ++reg)
        sq[reg] = SQ[b * 4096 + strip * 64 + (h * 2 + rt) * 16 + q * 4 + reg];
    }
#pragma unroll
    for (int nt = 0; nt < 8; ++nt)
#pragma unroll
      for (int reg = 0; reg < 4; ++reg) {
        const float raw = acc[rt][nt][reg];
        float sv = fmaf(w, raw, bias);
        if (own && nt == ntd) {                      // predicated select, no indexing
          sv = fmaf(w * (1.f / 15.f), 16.f * raw - sq[reg], bias);
          ssum += sv;
        }
        acc[rt][nt][reg] = sv;
      }
#pragma unroll
    for (int reg = 0; reg < 4; ++reg) {
      float mx = acc[rt][0][reg];
#pragma unroll
      for (int nt = 1; nt < 8; ++nt) mx = fmaxf(mx, acc[rt][nt][reg]);
#pragma unroll
      for (int mk = 1; mk < 16; mk <<= 1) mx = fmaxf(mx, __shfl_xor(mx, mk, 64));
      if (cl_ == 0) lmx[c][(h * 2 + rt) * 16 + q * 4 + reg] = mx;
    }
  }
  __syncthreads();

#pragma unroll
  for (int rt = 0; rt < 2; ++rt)
#pragma unroll
    for (int reg = 0; reg < 4; ++reg) {
      const int Rl = (h * 2 + rt) * 16 + q * 4 + reg;
      const float mx = fmaxf(lmx[0][Rl], lmx[1][Rl]);
      float se = 0.f;
#pragma unroll
      for (int nt = 0; nt < 8; ++nt) se += __expf(acc[rt][nt][reg] - mx);
#pragma unroll
      for (int mk = 1; mk < 16; mk <<= 1) se += __shfl_xor(se, mk, 64);
      if (cl_ == 0) lsm[c][Rl] = se;
    }
  __syncthreads();

  float part = -ssum;
  if (c == 0 && cl_ == 0) {
#pragma unroll
    for (int rt = 0; rt < 2; ++rt)
#pragma unroll
      for (int reg = 0; reg < 4; ++reg) {
        const int Rl = (h * 2 + rt) * 16 + q * 4 + reg;
        const float mx = fmaxf(lmx[0][Rl], lmx[1][Rl]);
        part += mx + __logf(lsm[0][Rl] + lsm[1][Rl]);
      }
  }
#pragma unroll
  for (int mk = 1; mk < 64; mk <<= 1) part += __shfl_xor(part, mk, 64);
  if (lane == 0) bred[wid] = part;
  __syncthreads();
  if (tid == 0) atomicAdd(out, bred[0] + bred[1] + bred[2] + bred[3]);
}

extern "C" void kernel_launch(void* const* d_in, const int* in_sizes, int n_in,
                              void* d_out, int out_size, void* d_ws, size_t ws_size,
                              hipStream_t stream) {
  const float* e = (const float*)d_in[0];
  const float* wp = (const float*)d_in[1];
  const float* bp = (const float*)d_in[2];
  float* out = (float*)d_out;
  char* ws = (char*)d_ws;
  uint4* EbfA = (uint4*)ws;                              // 16 MB
  uint4* Cbf = (uint4*)(ws + (size_t)16 * 1024 * 1024);  // 1 MB
  float* SQ = (float*)(ws + (size_t)17 * 1024 * 1024);   // 128 KB

  k_prep<<<B * N, 256, 0, stream>>>(e, EbfA, Cbf, SQ, out);
  k_gemm<<<B * 64, 256, 0, stream>>>(EbfA, Cbf, SQ, wp, bp, out);
}